// Round 1
// baseline (286.763 us; speedup 1.0000x reference)
//
#include <hip/hip_runtime.h>
#include <hip/hip_cooperative_groups.h>
#include <math.h>

namespace cg = cooperative_groups;

typedef short bf16x8 __attribute__((ext_vector_type(8)));
typedef float f32x16 __attribute__((ext_vector_type(16)));

__device__ __forceinline__ unsigned short f2bf(float f) {
    union { float f; unsigned u; } x; x.f = f;
    unsigned r = x.u + 0x7FFFu + ((x.u >> 16) & 1u);
    return (unsigned short)(r >> 16);
}

// ---- One 64-k chunk of a 32-row tile transpose: fp32 row-major -> frag-major bf16.
// Bias folded at k==Kreal (bias==nullptr -> 1.0). Rows >= rowlimit are zero.
// dst tile layout: (ks, 64 lanes, 8) with o = lane&31, k = ks*16 + (lane>>5)*8 + j.
__device__ __forceinline__ void do_chunk(
    const float* __restrict__ W, const float* __restrict__ bias,
    int rowbase, int rowlimit, int Kreal, int ldsrc,
    unsigned short* __restrict__ dst, int kc, float* s, int tid)
{
    const int r = tid >> 3, l = tid & 7;           // staging: row r, 8 lanes/row
    const int ks_l = tid >> 6, lane = tid & 63;    // gather: wave ks_l owns ks
    const int m = lane & 31, h = lane >> 5;
    {   // stage 32 rows x 64 k into LDS (stride 66: 2-way-max bank aliasing = free)
        int kb = kc * 64 + l * 8;
        const bool rv = r < rowlimit;
        const float* src = W + (size_t)(rowbase + r) * ldsrc + kb;
        float v[8];
        if (rv && kb + 7 < Kreal) {
            #pragma unroll
            for (int i = 0; i < 8; ++i) v[i] = src[i];
        } else {
            #pragma unroll
            for (int i = 0; i < 8; ++i) {
                int k = kb + i;
                v[i] = (rv && k < Kreal) ? src[i]
                     : ((rv && k == Kreal) ? (bias ? bias[rowbase + r] : 1.0f) : 0.f);
            }
        }
        #pragma unroll
        for (int i = 0; i < 8; ++i) s[r * 66 + l * 8 + i] = v[i];
    }
    __syncthreads();
    {   // frag gather + bf16 convert + coalesced 16B store
        bf16x8 pk;
        #pragma unroll
        for (int j = 0; j < 8; ++j)
            pk[j] = (short)f2bf(s[m * 66 + ks_l * 16 + h * 8 + j]);
        *(bf16x8*)(dst + ((size_t)(kc * 4 + ks_l) * 64 + lane) * 8) = pk;
    }
    __syncthreads();   // LDS reusable for the next job
}

// ---------------- Layer: tile 32o x 32b x 4 banks; 4-wave split-K -----------------
// Register double-buffered K-loop (chunks of 3 steps, ~15 loads in flight).
// Parallel epilogue: all waves dump partial planes to LDS; wave w reduces g=w rows.
template<bool ELU, bool OUT_BF16, int KP, int OPAD>
__device__ __forceinline__ void layer_phase(
    const unsigned short* __restrict__ Wf,   // (4, OPAD/32, KP/16, 64, 8)
    const unsigned short* __restrict__ Hf,   // (32, KP/16, 64, 8)
    const float* __restrict__ coef,          // (1024, 4)
    unsigned short* __restrict__ HoutF,      // frag-major (32, 36, 64, 8)  [OUT_BF16]
    float* __restrict__ outF, int Oreal,     // (1024, Oreal) row-major     [!OUT_BF16]
    float* red, int bid, int tid)
{
    constexpr int NOT = OPAD / 32, NKS = KP / 16, KSQ = NKS / 4;
    constexpr int CH = 3, NC2 = KSQ / CH;    // 6->2, 9->3
    const int lane = tid & 63, w = tid >> 6;
    const int m = lane & 31, h = lane >> 5;
    const size_t nstr = (size_t)NOT * NKS * 512;

    const int ot = bid >> 5, bt = bid & 31;
    const unsigned short* wbase = Wf + ((size_t)ot * NKS + w * KSQ) * 512 + (size_t)lane * 8;
    const unsigned short* bbase = Hf + ((size_t)bt * NKS + w * KSQ) * 512 + (size_t)lane * 8;

    f32x16 acc0 = {}, acc1 = {}, acc2 = {}, acc3 = {};
    bf16x8 Ab[2][CH][4], Bb[2][CH];

    #pragma unroll
    for (int sI = 0; sI < CH; ++sI) {
        Bb[0][sI] = *(const bf16x8*)(bbase + (size_t)sI * 512);
        #pragma unroll
        for (int n = 0; n < 4; ++n)
            Ab[0][sI][n] = *(const bf16x8*)(wbase + (size_t)n * nstr + (size_t)sI * 512);
    }
    #pragma unroll
    for (int c = 0; c < NC2; ++c) {
        const int cur = c & 1;
        if (c + 1 < NC2) {
            const int nxt = cur ^ 1;
            #pragma unroll
            for (int sI = 0; sI < CH; ++sI) {
                int st = (c + 1) * CH + sI;
                Bb[nxt][sI] = *(const bf16x8*)(bbase + (size_t)st * 512);
                #pragma unroll
                for (int n = 0; n < 4; ++n)
                    Ab[nxt][sI][n] = *(const bf16x8*)(wbase + (size_t)n * nstr + (size_t)st * 512);
            }
        }
        #pragma unroll
        for (int sI = 0; sI < CH; ++sI) {
            acc0 = __builtin_amdgcn_mfma_f32_32x32x16_bf16(Ab[cur][sI][0], Bb[cur][sI], acc0, 0, 0, 0);
            acc1 = __builtin_amdgcn_mfma_f32_32x32x16_bf16(Ab[cur][sI][1], Bb[cur][sI], acc1, 0, 0, 0);
            acc2 = __builtin_amdgcn_mfma_f32_32x32x16_bf16(Ab[cur][sI][2], Bb[cur][sI], acc2, 0, 0, 0);
            acc3 = __builtin_amdgcn_mfma_f32_32x32x16_bf16(Ab[cur][sI][3], Bb[cur][sI], acc3, 0, 0, 0);
        }
    }

    // coef combine (per-wave partial), dump plane w to LDS
    const int b = bt * 32 + m;
    float4 cf = *(const float4*)(coef + b * 4);
    #pragma unroll
    for (int g = 0; g < 4; ++g)
        #pragma unroll
        for (int j = 0; j < 4; ++j) {
            int rI = g * 4 + j;
            float v = cf.x * acc0[rI] + cf.y * acc1[rI] + cf.z * acc2[rI] + cf.w * acc3[rI];
            red[w * 1024 + (8 * g + 4 * h + j) * 32 + m] = v;
        }
    __syncthreads();
    // wave w reduces + stores rows of group g=w
    {
        float vv[4];
        #pragma unroll
        for (int j = 0; j < 4; ++j) {
            int row = 8 * w + 4 * h + j;
            float v = red[row * 32 + m] + red[1024 + row * 32 + m]
                    + red[2048 + row * 32 + m] + red[3072 + row * 32 + m];
            if (ELU) v = (v > 0.f) ? v : expm1f(v);
            vv[j] = v;
        }
        if (OUT_BF16) {
            // o = ot*32 + 8w + 4h + j -> next layer's B-frag pos (NKS_next = 36)
            size_t off = (((size_t)bt * 36 + ot * 2 + (w >> 1)) * 64
                          + (w & 1) * 32 + m) * 8 + 4 * h;
            ushort4 pk;
            pk.x = f2bf(vv[0]); pk.y = f2bf(vv[1]); pk.z = f2bf(vv[2]); pk.w = f2bf(vv[3]);
            *(ushort4*)(HoutF + off) = pk;
        } else {
            int orow = ot * 32 + 8 * w + 4 * h;
            #pragma unroll
            for (int j = 0; j < 4; ++j)
                if (orow + j < Oreal) outF[(size_t)b * Oreal + orow + j] = vv[j];
        }
    }
    __syncthreads();   // red reusable / safe before next phase
}

// ---------------- Fused cooperative kernel: phaseA -> L0 -> L1 -> L2 --------------
// 512 blocks x 256 threads, 2 blocks/CU co-resident (cooperative launch verified by
// __launch_bounds__(256,2): VGPR<=256). Phase A re-chunked into 1512 chunk-jobs
// spread over all 512 blocks (<=3 serial chunks/block vs 9 on 200 blocks before).
__global__ void __launch_bounds__(256, 2) fused_kernel(
    const float* __restrict__ x,
    const float* __restrict__ W0, const float* __restrict__ W1, const float* __restrict__ W2,
    const float* __restrict__ bias0, const float* __restrict__ bias1, const float* __restrict__ bias2,
    float* __restrict__ coef, unsigned short* __restrict__ xf,
    unsigned short* __restrict__ H1f, unsigned short* __restrict__ H2f,
    unsigned short* __restrict__ Wf0, unsigned short* __restrict__ Wf1, unsigned short* __restrict__ Wf2,
    float* __restrict__ outF)
{
    __shared__ float sm[4096];   // phaseA stage (2112 floats) / layer red (4096 floats)
    const int bid = blockIdx.x, tid = threadIdx.x;
    cg::grid_group grid = cg::this_grid();

    // ---- Phase A: coef + constant tails (blocks 0..31) ----
    if (bid < 32) {
        const int bt = bid;
        if (tid < 32) {
            int b = bt * 32 + tid;
            float phase = x[(size_t)b * 343 + 342];
            float ps = 4.0f * phase;
            int k1 = (int)ps;
            float mu = ps - (float)k1;
            k1 &= 3;
            float mu2 = mu * mu, mu3 = mu2 * mu;
            float c0 = -0.5f * mu3 +        mu2 - 0.5f * mu;
            float c1 =  1.5f * mu3 - 2.5f * mu2 + 1.0f;
            float c2 = -1.5f * mu3 + 2.0f * mu2 + 0.5f * mu;
            float c3 =  0.5f * mu3 - 0.5f * mu2;
            float cc[4];
            cc[(k1 + 3) & 3] = c0;
            cc[k1]           = c1;
            cc[(k1 + 1) & 3] = c2;
            cc[(k1 + 2) & 3] = c3;
            *(float4*)(coef + b * 4) = make_float4(cc[0], cc[1], cc[2], cc[3]);
        }
        {   // H1f/H2f constant tails: ks 32..35 (k==512 -> 1.0)
            int kk = tid >> 6, lane = tid & 63;
            size_t off = ((size_t)(bt * 36 + 32 + kk) * 64 + lane) * 8;
            bf16x8 v;
            #pragma unroll
            for (int j = 0; j < 8; ++j)
                v[j] = (short)((kk == 0 && (lane >> 5) == 0 && j == 0) ? 0x3F80 : 0);
            *(bf16x8*)(H1f + off) = v;
            *(bf16x8*)(H2f + off) = v;
        }
    }

    // ---- Phase A: 1512 transpose chunk-jobs over all 512 blocks ----
    // jobs: [0,192) xf | [192,576) W0 | [576,1152) W1 | [1152,1512) W2
    for (int j = bid; j < 1512; j += 512) {
        if (j < 192) {
            int bt = j / 6, kc = j % 6;
            do_chunk(x, nullptr, bt * 32, 32, 342, 343,
                     xf + (size_t)bt * 24 * 512, kc, sm, tid);
        } else if (j < 576) {
            int t = j - 192, tile = t / 6, kc = t % 6, n = tile >> 4, ot = tile & 15;
            do_chunk(W0, bias0, n * 512 + ot * 32, 32, 342, 342,
                     Wf0 + (size_t)(n * 16 + ot) * 24 * 512, kc, sm, tid);
        } else if (j < 1152) {
            int t = j - 576, tile = t / 9, kc = t % 9, n = tile >> 4, ot = tile & 15;
            do_chunk(W1, bias1, n * 512 + ot * 32, 32, 512, 512,
                     Wf1 + (size_t)(n * 16 + ot) * 36 * 512, kc, sm, tid);
        } else {
            int t = j - 1152, tile = t / 9, kc = t % 9, n = tile / 10, ot = tile % 10;
            int rl = 311 - ot * 32; if (rl > 32) rl = 32;
            do_chunk(W2, bias2, n * 311 + ot * 32, rl, 512, 512,
                     Wf2 + (size_t)(n * 10 + ot) * 36 * 512, kc, sm, tid);
        }
    }

    grid.sync();
    layer_phase<true,  true,  384, 512>(Wf0, xf,  coef, H1f, nullptr, 512, sm, bid, tid);
    grid.sync();
    layer_phase<true,  true,  576, 512>(Wf1, H1f, coef, H2f, nullptr, 512, sm, bid, tid);
    grid.sync();
    if (bid < 320)
        layer_phase<false, false, 576, 320>(Wf2, H2f, coef, nullptr, outF, 311, sm, bid, tid);
}

extern "C" void kernel_launch(void* const* d_in, const int* in_sizes, int n_in,
                              void* d_out, int out_size, void* d_ws, size_t ws_size,
                              hipStream_t stream) {
    (void)in_sizes; (void)n_in; (void)out_size; (void)ws_size;
    const float* x  = (const float*)d_in[0];
    const float* W0 = (const float*)d_in[1];
    const float* W1 = (const float*)d_in[2];
    const float* W2 = (const float*)d_in[3];
    const float* b0 = (const float*)d_in[4];
    const float* b1 = (const float*)d_in[5];
    const float* b2 = (const float*)d_in[6];
    float* out = (float*)d_out;

    char* wsb = (char*)d_ws;
    float*          coef = (float*)(wsb + 0);                  //   16384 B
    unsigned short* xf   = (unsigned short*)(wsb + 16384);     // (32,24,64,8)
    unsigned short* H1f  = (unsigned short*)(wsb + 802816);    // (32,36,64,8)
    unsigned short* H2f  = (unsigned short*)(wsb + 1982464);   // (32,36,64,8)
    unsigned short* Wf0  = (unsigned short*)(wsb + 3162112);   // (4,16,24,64,8)
    unsigned short* Wf1  = (unsigned short*)(wsb + 4734976);   // (4,16,36,64,8)
    unsigned short* Wf2  = (unsigned short*)(wsb + 7094272);   // (4,10,36,64,8)

    void* args[] = { (void*)&x, (void*)&W0, (void*)&W1, (void*)&W2,
                     (void*)&b0, (void*)&b1, (void*)&b2,
                     (void*)&coef, (void*)&xf, (void*)&H1f, (void*)&H2f,
                     (void*)&Wf0, (void*)&Wf1, (void*)&Wf2, (void*)&out };
    hipLaunchCooperativeKernel((const void*)fused_kernel, dim3(512), dim3(256),
                               args, 0, stream);
}

// Round 3
// 191.699 us; speedup vs baseline: 1.4959x; 1.4959x over previous
//
#include <hip/hip_runtime.h>
#include <math.h>

typedef short bf16x8 __attribute__((ext_vector_type(8)));
typedef float f32x16 __attribute__((ext_vector_type(16)));

#define AS __HIP_MEMORY_SCOPE_AGENT

// Per-tile ready counters (zeroed by hipMemsetAsync before launch).
struct Flags {
    unsigned coefR[32];  // coef+tails for bt written           (target 1)
    unsigned xfR[32];    // xf tile bt: 6 chunks                (target 6)
    unsigned w0R[16];    // Wf0 slice ot: 4 banks x 6 chunks    (target 24)
    unsigned w1R[16];    // Wf1 slice ot: 4 banks x 9 chunks    (target 36)
    unsigned w2R[16];    // Wf2 slice ot: 4 banks x 9 chunks    (target 36)
    unsigned h1R[32];    // H1f tile bt: 16 L0 blocks           (target 16)
    unsigned h2R[32];    // H2f tile bt: 16 L1 blocks           (target 16)
};

__device__ __forceinline__ void signal_done(unsigned* c) {
    // caller: tid==0, AFTER a __syncthreads() (drains vmcnt -> stores in L2)
    __builtin_amdgcn_fence(__ATOMIC_RELEASE, "agent");   // L2 writeback
    __hip_atomic_fetch_add(c, 1u, __ATOMIC_RELAXED, AS);
}
__device__ __forceinline__ void wait_ge(const unsigned* c, unsigned tgt) {
    while (__hip_atomic_load(c, __ATOMIC_RELAXED, AS) < tgt)
        __builtin_amdgcn_s_sleep(2);
}

__device__ __forceinline__ unsigned short f2bf(float f) {
    union { float f; unsigned u; } x; x.f = f;
    unsigned r = x.u + 0x7FFFu + ((x.u >> 16) & 1u);
    return (unsigned short)(r >> 16);
}

// ---- One 64-k chunk of a 32-row tile transpose: fp32 row-major -> frag-major bf16.
// Bias folded at k==Kreal (bias==nullptr -> 1.0). Rows >= rowlimit are zero.
// dst tile layout: (ks, 64 lanes, 8) with o = lane&31, k = ks*16 + (lane>>5)*8 + j.
__device__ __forceinline__ void do_chunk(
    const float* __restrict__ W, const float* __restrict__ bias,
    int rowbase, int rowlimit, int Kreal, int ldsrc,
    unsigned short* __restrict__ dst, int kc, float* s, int tid)
{
    const int r = tid >> 3, l = tid & 7;           // staging: row r, 8 lanes/row
    const int ks_l = tid >> 6, lane = tid & 63;    // gather: wave ks_l owns ks
    const int m = lane & 31, h = lane >> 5;
    {   // stage 32 rows x 64 k into LDS (stride 66: 2-way-max bank aliasing = free)
        int kb = kc * 64 + l * 8;
        const bool rv = r < rowlimit;
        const float* src = W + (size_t)(rowbase + r) * ldsrc + kb;
        float v[8];
        if (rv && kb + 7 < Kreal) {
            #pragma unroll
            for (int i = 0; i < 8; ++i) v[i] = src[i];
        } else {
            #pragma unroll
            for (int i = 0; i < 8; ++i) {
                int k = kb + i;
                v[i] = (rv && k < Kreal) ? src[i]
                     : ((rv && k == Kreal) ? (bias ? bias[rowbase + r] : 1.0f) : 0.f);
            }
        }
        #pragma unroll
        for (int i = 0; i < 8; ++i) s[r * 66 + l * 8 + i] = v[i];
    }
    __syncthreads();
    {   // frag gather + bf16 convert + coalesced 16B store
        bf16x8 pk;
        #pragma unroll
        for (int j = 0; j < 8; ++j)
            pk[j] = (short)f2bf(s[m * 66 + ks_l * 16 + h * 8 + j]);
        *(bf16x8*)(dst + ((size_t)(kc * 4 + ks_l) * 64 + lane) * 8) = pk;
    }
    __syncthreads();   // LDS reusable + stores drained before signal
}

// ---------------- Layer: tile 32o x 32b x 4 banks; 4-wave split-K -----------------
template<bool ELU, bool OUT_BF16, int KP, int OPAD>
__device__ __forceinline__ void layer_phase(
    const unsigned short* __restrict__ Wf,   // (4, OPAD/32, KP/16, 64, 8)
    const unsigned short* __restrict__ Hf,   // (32, KP/16, 64, 8)
    const float* __restrict__ coef,          // (1024, 4)
    unsigned short* __restrict__ HoutF,      // frag-major (32, 36, 64, 8)  [OUT_BF16]
    float* __restrict__ outF, int Oreal,     // (1024, Oreal) row-major     [!OUT_BF16]
    float* red, int bid, int tid)
{
    constexpr int NOT = OPAD / 32, NKS = KP / 16, KSQ = NKS / 4;
    constexpr int CH = 3, NC2 = KSQ / CH;    // 6->2, 9->3
    const int lane = tid & 63, w = tid >> 6;
    const int m = lane & 31, h = lane >> 5;
    const size_t nstr = (size_t)NOT * NKS * 512;

    const int ot = bid >> 5, bt = bid & 31;
    const unsigned short* wbase = Wf + ((size_t)ot * NKS + w * KSQ) * 512 + (size_t)lane * 8;
    const unsigned short* bbase = Hf + ((size_t)bt * NKS + w * KSQ) * 512 + (size_t)lane * 8;

    f32x16 acc0 = {}, acc1 = {}, acc2 = {}, acc3 = {};
    bf16x8 Ab[2][CH][4], Bb[2][CH];

    #pragma unroll
    for (int sI = 0; sI < CH; ++sI) {
        Bb[0][sI] = *(const bf16x8*)(bbase + (size_t)sI * 512);
        #pragma unroll
        for (int n = 0; n < 4; ++n)
            Ab[0][sI][n] = *(const bf16x8*)(wbase + (size_t)n * nstr + (size_t)sI * 512);
    }
    #pragma unroll
    for (int c = 0; c < NC2; ++c) {
        const int cur = c & 1;
        if (c + 1 < NC2) {
            const int nxt = cur ^ 1;
            #pragma unroll
            for (int sI = 0; sI < CH; ++sI) {
                int st = (c + 1) * CH + sI;
                Bb[nxt][sI] = *(const bf16x8*)(bbase + (size_t)st * 512);
                #pragma unroll
                for (int n = 0; n < 4; ++n)
                    Ab[nxt][sI][n] = *(const bf16x8*)(wbase + (size_t)n * nstr + (size_t)st * 512);
            }
        }
        #pragma unroll
        for (int sI = 0; sI < CH; ++sI) {
            acc0 = __builtin_amdgcn_mfma_f32_32x32x16_bf16(Ab[cur][sI][0], Bb[cur][sI], acc0, 0, 0, 0);
            acc1 = __builtin_amdgcn_mfma_f32_32x32x16_bf16(Ab[cur][sI][1], Bb[cur][sI], acc1, 0, 0, 0);
            acc2 = __builtin_amdgcn_mfma_f32_32x32x16_bf16(Ab[cur][sI][2], Bb[cur][sI], acc2, 0, 0, 0);
            acc3 = __builtin_amdgcn_mfma_f32_32x32x16_bf16(Ab[cur][sI][3], Bb[cur][sI], acc3, 0, 0, 0);
        }
    }

    // coef combine (per-wave partial), dump plane w to LDS
    const int b = bt * 32 + m;
    float4 cf = *(const float4*)(coef + b * 4);
    #pragma unroll
    for (int g = 0; g < 4; ++g)
        #pragma unroll
        for (int j = 0; j < 4; ++j) {
            int rI = g * 4 + j;
            float v = cf.x * acc0[rI] + cf.y * acc1[rI] + cf.z * acc2[rI] + cf.w * acc3[rI];
            red[w * 1024 + (8 * g + 4 * h + j) * 32 + m] = v;
        }
    __syncthreads();
    // wave w reduces + stores rows of group g=w
    {
        float vv[4];
        #pragma unroll
        for (int j = 0; j < 4; ++j) {
            int row = 8 * w + 4 * h + j;
            float v = red[row * 32 + m] + red[1024 + row * 32 + m]
                    + red[2048 + row * 32 + m] + red[3072 + row * 32 + m];
            if (ELU) v = (v > 0.f) ? v : expm1f(v);
            vv[j] = v;
        }
        if (OUT_BF16) {
            // o = ot*32 + 8w + 4h + j -> next layer's B-frag pos (NKS_next = 36)
            size_t off = (((size_t)bt * 36 + ot * 2 + (w >> 1)) * 64
                          + (w & 1) * 32 + m) * 8 + 4 * h;
            ushort4 pk;
            pk.x = f2bf(vv[0]); pk.y = f2bf(vv[1]); pk.z = f2bf(vv[2]); pk.w = f2bf(vv[3]);
            *(ushort4*)(HoutF + off) = pk;
        } else {
            int orow = ot * 32 + 8 * w + 4 * h;
            #pragma unroll
            for (int j = 0; j < 4; ++j)
                if (orow + j < Oreal) outF[(size_t)b * Oreal + orow + j] = vv[j];
        }
    }
    __syncthreads();   // red reusable + output stores drained before signal
}

// ---------------- Fused dataflow kernel: per-tile ready flags, no grid barrier ----
// 512 blocks x 256 threads, 2/CU co-resident (cooperative launch = residency
// guarantee only; cg::grid.sync is NOT used -- it cost ~60us/sync in round 1).
__global__ void __launch_bounds__(256, 2) fused_kernel(
    const float* __restrict__ x,
    const float* __restrict__ W0, const float* __restrict__ W1, const float* __restrict__ W2,
    const float* __restrict__ bias0, const float* __restrict__ bias1, const float* __restrict__ bias2,
    float* __restrict__ coef, unsigned short* __restrict__ xf,
    unsigned short* __restrict__ H1f, unsigned short* __restrict__ H2f,
    unsigned short* __restrict__ Wf0, unsigned short* __restrict__ Wf1, unsigned short* __restrict__ Wf2,
    float* __restrict__ outF, Flags* fl)
{
    __shared__ float sm[4096];   // phaseA stage (2112 floats) / layer red (4096 floats)
    const int bid = blockIdx.x, tid = threadIdx.x;

    // ---- coef + constant tails (blocks 0..31), then signal coefR[bt] ----
    if (bid < 32) {
        const int bt = bid;
        if (tid < 32) {
            int b = bt * 32 + tid;
            float phase = x[(size_t)b * 343 + 342];
            float ps = 4.0f * phase;
            int k1 = (int)ps;
            float mu = ps - (float)k1;
            k1 &= 3;
            float mu2 = mu * mu, mu3 = mu2 * mu;
            float c0 = -0.5f * mu3 +        mu2 - 0.5f * mu;
            float c1 =  1.5f * mu3 - 2.5f * mu2 + 1.0f;
            float c2 = -1.5f * mu3 + 2.0f * mu2 + 0.5f * mu;
            float c3 =  0.5f * mu3 - 0.5f * mu2;
            float cc[4];
            cc[(k1 + 3) & 3] = c0;
            cc[k1]           = c1;
            cc[(k1 + 1) & 3] = c2;
            cc[(k1 + 2) & 3] = c3;
            *(float4*)(coef + b * 4) = make_float4(cc[0], cc[1], cc[2], cc[3]);
        }
        {   // H1f/H2f constant tails: ks 32..35 (k==512 -> 1.0)
            int kk = tid >> 6, lane = tid & 63;
            size_t off = ((size_t)(bt * 36 + 32 + kk) * 64 + lane) * 8;
            bf16x8 v;
            #pragma unroll
            for (int j = 0; j < 8; ++j)
                v[j] = (short)((kk == 0 && (lane >> 5) == 0 && j == 0) ? 0x3F80 : 0);
            *(bf16x8*)(H1f + off) = v;
            *(bf16x8*)(H2f + off) = v;
        }
        __syncthreads();
        if (tid == 0) signal_done(&fl->coefR[bt]);
    }

    // ---- Phase A: 1512 transpose chunk-jobs, signal per chunk ----
    // jobs: [0,192) xf | [192,576) W0 | [576,1152) W1 | [1152,1512) W2
    for (int j = bid; j < 1512; j += 512) {
        unsigned* sig;
        if (j < 192) {
            int bt = j / 6, kc = j % 6;
            do_chunk(x, nullptr, bt * 32, 32, 342, 343,
                     xf + (size_t)bt * 24 * 512, kc, sm, tid);
            sig = &fl->xfR[bt];
        } else if (j < 576) {
            int t = j - 192, tile = t / 6, kc = t % 6;          // tile = n*16+ot
            do_chunk(W0, bias0, (tile >> 4) * 512 + (tile & 15) * 32, 32, 342, 342,
                     Wf0 + (size_t)tile * 24 * 512, kc, sm, tid);
            sig = &fl->w0R[tile & 15];
        } else if (j < 1152) {
            int t = j - 576, tile = t / 9, kc = t % 9;          // tile = n*16+ot
            do_chunk(W1, bias1, (tile >> 4) * 512 + (tile & 15) * 32, 32, 512, 512,
                     Wf1 + (size_t)tile * 36 * 512, kc, sm, tid);
            sig = &fl->w1R[tile & 15];
        } else {
            int t = j - 1152, tile = t / 9, kc = t % 9;         // tile = n*10+ot
            int n = tile / 10, ot = tile % 10;
            int rl = 311 - ot * 32; if (rl > 32) rl = 32;
            do_chunk(W2, bias2, n * 311 + ot * 32, rl, 512, 512,
                     Wf2 + (size_t)tile * 36 * 512, kc, sm, tid);
            sig = &fl->w2R[ot];
        }
        if (tid == 0) signal_done(sig);
    }

    const int ot = bid >> 5, bt = bid & 31;

    // ---- Layer 0: wait Wf0[ot], xf[bt], coef[bt] ----
    if (tid == 0) {
        wait_ge(&fl->w0R[ot], 24);
        wait_ge(&fl->xfR[bt], 6);
        wait_ge(&fl->coefR[bt], 1);
        __builtin_amdgcn_fence(__ATOMIC_ACQUIRE, "agent");
    }
    __syncthreads();
    layer_phase<true, true, 384, 512>(Wf0, xf, coef, H1f, nullptr, 512, sm, bid, tid);
    if (tid == 0) signal_done(&fl->h1R[bt]);

    // ---- Layer 1: wait Wf1[ot], H1f[bt] (16 producers; tail chained via coefR->L0) ----
    if (tid == 0) {
        wait_ge(&fl->w1R[ot], 36);
        wait_ge(&fl->h1R[bt], 16);
        __builtin_amdgcn_fence(__ATOMIC_ACQUIRE, "agent");
    }
    __syncthreads();
    layer_phase<true, true, 576, 512>(Wf1, H1f, coef, H2f, nullptr, 512, sm, bid, tid);
    if (tid == 0) signal_done(&fl->h2R[bt]);

    // ---- Layer 2 (blocks 0..319): wait Wf2[ot], H2f[bt] ----
    if (bid < 320) {
        if (tid == 0) {
            wait_ge(&fl->w2R[ot], 36);
            wait_ge(&fl->h2R[bt], 16);
            __builtin_amdgcn_fence(__ATOMIC_ACQUIRE, "agent");
        }
        __syncthreads();
        layer_phase<false, false, 576, 320>(Wf2, H2f, coef, nullptr, outF, 311, sm, bid, tid);
    }
}

extern "C" void kernel_launch(void* const* d_in, const int* in_sizes, int n_in,
                              void* d_out, int out_size, void* d_ws, size_t ws_size,
                              hipStream_t stream) {
    (void)in_sizes; (void)n_in; (void)out_size; (void)ws_size;
    const float* x  = (const float*)d_in[0];
    const float* W0 = (const float*)d_in[1];
    const float* W1 = (const float*)d_in[2];
    const float* W2 = (const float*)d_in[3];
    const float* b0 = (const float*)d_in[4];
    const float* b1 = (const float*)d_in[5];
    const float* b2 = (const float*)d_in[6];
    float* out = (float*)d_out;

    char* wsb = (char*)d_ws;
    float*          coef = (float*)(wsb + 0);                  //   16384 B
    unsigned short* xf   = (unsigned short*)(wsb + 16384);     // (32,24,64,8)
    unsigned short* H1f  = (unsigned short*)(wsb + 802816);    // (32,36,64,8)
    unsigned short* H2f  = (unsigned short*)(wsb + 1982464);   // (32,36,64,8)
    unsigned short* Wf0  = (unsigned short*)(wsb + 3162112);   // (4,16,24,64,8)
    unsigned short* Wf1  = (unsigned short*)(wsb + 4734976);   // (4,16,36,64,8)
    unsigned short* Wf2  = (unsigned short*)(wsb + 7094272);   // (4,10,36,64,8)
    Flags*          fl   = (Flags*)(wsb + 8650752);            // counters

    hipMemsetAsync(fl, 0, sizeof(Flags), stream);

    void* args[] = { (void*)&x, (void*)&W0, (void*)&W1, (void*)&W2,
                     (void*)&b0, (void*)&b1, (void*)&b2,
                     (void*)&coef, (void*)&xf, (void*)&H1f, (void*)&H2f,
                     (void*)&Wf0, (void*)&Wf1, (void*)&Wf2, (void*)&out,
                     (void*)&fl };
    hipLaunchCooperativeKernel((const void*)fused_kernel, dim3(512), dim3(256),
                               args, 0, stream);
}

// Round 4
// 92.188 us; speedup vs baseline: 3.1106x; 2.0794x over previous
//
#include <hip/hip_runtime.h>
#include <math.h>

typedef short bf16x8 __attribute__((ext_vector_type(8)));
typedef float f32x16 __attribute__((ext_vector_type(16)));

__device__ __forceinline__ unsigned short f2bf(float f) {
    union { float f; unsigned u; } x; x.f = f;
    unsigned r = x.u + 0x7FFFu + ((x.u >> 16) & 1u);
    return (unsigned short)(r >> 16);
}

// ---- One 64-k chunk of a 32-row tile transpose: fp32 row-major -> frag-major bf16.
// Bias folded at k==Kreal (bias==nullptr -> 1.0). Rows >= rowlimit are zero.
// dst tile layout: (ks, 64 lanes, 8) with o = lane&31, k = ks*16 + (lane>>5)*8 + j.
__device__ __forceinline__ void do_chunk(
    const float* __restrict__ W, const float* __restrict__ bias,
    int rowbase, int rowlimit, int Kreal, int ldsrc,
    unsigned short* __restrict__ dst, int kc, float* s, int tid)
{
    const int r = tid >> 3, l = tid & 7;           // staging: row r, 8 lanes/row
    const int ks_l = tid >> 6, lane = tid & 63;    // gather: wave ks_l owns ks
    const int m = lane & 31, h = lane >> 5;
    {   // stage 32 rows x 64 k into LDS (stride 66: 2-way-max bank aliasing = free)
        int kb = kc * 64 + l * 8;
        const bool rv = r < rowlimit;
        const float* src = W + (size_t)(rowbase + r) * ldsrc + kb;
        float v[8];
        if (rv && kb + 7 < Kreal) {
            #pragma unroll
            for (int i = 0; i < 8; ++i) v[i] = src[i];
        } else {
            #pragma unroll
            for (int i = 0; i < 8; ++i) {
                int k = kb + i;
                v[i] = (rv && k < Kreal) ? src[i]
                     : ((rv && k == Kreal) ? (bias ? bias[rowbase + r] : 1.0f) : 0.f);
            }
        }
        #pragma unroll
        for (int i = 0; i < 8; ++i) s[r * 66 + l * 8 + i] = v[i];
    }
    __syncthreads();
    {   // frag gather + bf16 convert + coalesced 16B store
        bf16x8 pk;
        #pragma unroll
        for (int j = 0; j < 8; ++j)
            pk[j] = (short)f2bf(s[m * 66 + ks_l * 16 + h * 8 + j]);
        *(bf16x8*)(dst + ((size_t)(kc * 4 + ks_l) * 64 + lane) * 8) = pk;
    }
}

// ---------------- Phase A: 1512 one-chunk transpose jobs + 32 coef/tail blocks ----
// bid: [0,192) xf | [192,576) W0 | [576,1152) W1 | [1152,1512) W2 | [1512,1544) coef
__global__ void __launch_bounds__(256) phaseA_kernel(
    const float* __restrict__ x,
    const float* __restrict__ W0, const float* __restrict__ W1, const float* __restrict__ W2,
    const float* __restrict__ bias0, const float* __restrict__ bias1, const float* __restrict__ bias2,
    float* __restrict__ coef, unsigned short* __restrict__ xf,
    unsigned short* __restrict__ H1f, unsigned short* __restrict__ H2f,
    unsigned short* __restrict__ Wf0, unsigned short* __restrict__ Wf1, unsigned short* __restrict__ Wf2)
{
    __shared__ float s[32 * 66];
    const int bid = blockIdx.x, tid = threadIdx.x;

    if (bid < 192) {
        int bt = bid / 6, kc = bid % 6;
        do_chunk(x, nullptr, bt * 32, 32, 342, 343,
                 xf + (size_t)bt * 24 * 512, kc, s, tid);
    } else if (bid < 576) {
        int t = bid - 192, tile = t / 6, kc = t % 6;           // tile = n*16+ot
        do_chunk(W0, bias0, (tile >> 4) * 512 + (tile & 15) * 32, 32, 342, 342,
                 Wf0 + (size_t)tile * 24 * 512, kc, s, tid);
    } else if (bid < 1152) {
        int t = bid - 576, tile = t / 9, kc = t % 9;           // tile = n*16+ot
        do_chunk(W1, bias1, (tile >> 4) * 512 + (tile & 15) * 32, 32, 512, 512,
                 Wf1 + (size_t)tile * 36 * 512, kc, s, tid);
    } else if (bid < 1512) {
        int t = bid - 1152, tile = t / 9, kc = t % 9;          // tile = n*10+ot
        int n = tile / 10, ot = tile % 10;
        int rl = 311 - ot * 32; if (rl > 32) rl = 32;
        do_chunk(W2, bias2, n * 311 + ot * 32, rl, 512, 512,
                 Wf2 + (size_t)tile * 36 * 512, kc, s, tid);
    } else {
        const int bt = bid - 1512;
        if (tid < 32) {
            int b = bt * 32 + tid;
            float phase = x[(size_t)b * 343 + 342];
            float ps = 4.0f * phase;
            int k1 = (int)ps;
            float mu = ps - (float)k1;
            k1 &= 3;
            float mu2 = mu * mu, mu3 = mu2 * mu;
            float c0 = -0.5f * mu3 +        mu2 - 0.5f * mu;
            float c1 =  1.5f * mu3 - 2.5f * mu2 + 1.0f;
            float c2 = -1.5f * mu3 + 2.0f * mu2 + 0.5f * mu;
            float c3 =  0.5f * mu3 - 0.5f * mu2;
            float cc[4];
            cc[(k1 + 3) & 3] = c0;
            cc[k1]           = c1;
            cc[(k1 + 1) & 3] = c2;
            cc[(k1 + 2) & 3] = c3;
            *(float4*)(coef + b * 4) = make_float4(cc[0], cc[1], cc[2], cc[3]);
        }
        {   // H1f/H2f constant tails: ks 32..35 (k==512 -> 1.0)
            int kk = tid >> 6, lane = tid & 63;
            size_t off = ((size_t)(bt * 36 + 32 + kk) * 64 + lane) * 8;
            bf16x8 v;
            #pragma unroll
            for (int j = 0; j < 8; ++j)
                v[j] = (short)((kk == 0 && (lane >> 5) == 0 && j == 0) ? 0x3F80 : 0);
            *(bf16x8*)(H1f + off) = v;
            *(bf16x8*)(H2f + off) = v;
        }
    }
}

// ---------------- Layer: tile 32o x 32b x 4 banks; 4-wave split-K -----------------
// Register double-buffered K-loop (chunks of 3 steps, ~15 loads in flight).
// Parallel epilogue: all waves dump partial planes to LDS; wave w reduces g=w rows.
template<bool ELU, bool OUT_BF16, int KP, int OPAD>
__device__ __forceinline__ void layer_phase(
    const unsigned short* __restrict__ Wf,   // (4, OPAD/32, KP/16, 64, 8)
    const unsigned short* __restrict__ Hf,   // (32, KP/16, 64, 8)
    const float* __restrict__ coef,          // (1024, 4)
    unsigned short* __restrict__ HoutF,      // frag-major (32, 36, 64, 8)  [OUT_BF16]
    float* __restrict__ outF, int Oreal,     // (1024, Oreal) row-major     [!OUT_BF16]
    float* red, int bid, int tid)
{
    constexpr int NOT = OPAD / 32, NKS = KP / 16, KSQ = NKS / 4;
    constexpr int CH = 3, NC2 = KSQ / CH;    // 6->2, 9->3
    const int lane = tid & 63, w = tid >> 6;
    const int m = lane & 31, h = lane >> 5;
    const size_t nstr = (size_t)NOT * NKS * 512;

    const int ot = bid >> 5, bt = bid & 31;
    const unsigned short* wbase = Wf + ((size_t)ot * NKS + w * KSQ) * 512 + (size_t)lane * 8;
    const unsigned short* bbase = Hf + ((size_t)bt * NKS + w * KSQ) * 512 + (size_t)lane * 8;

    f32x16 acc0 = {}, acc1 = {}, acc2 = {}, acc3 = {};
    bf16x8 Ab[2][CH][4], Bb[2][CH];

    #pragma unroll
    for (int sI = 0; sI < CH; ++sI) {
        Bb[0][sI] = *(const bf16x8*)(bbase + (size_t)sI * 512);
        #pragma unroll
        for (int n = 0; n < 4; ++n)
            Ab[0][sI][n] = *(const bf16x8*)(wbase + (size_t)n * nstr + (size_t)sI * 512);
    }
    #pragma unroll
    for (int c = 0; c < NC2; ++c) {
        const int cur = c & 1;
        if (c + 1 < NC2) {
            const int nxt = cur ^ 1;
            #pragma unroll
            for (int sI = 0; sI < CH; ++sI) {
                int st = (c + 1) * CH + sI;
                Bb[nxt][sI] = *(const bf16x8*)(bbase + (size_t)st * 512);
                #pragma unroll
                for (int n = 0; n < 4; ++n)
                    Ab[nxt][sI][n] = *(const bf16x8*)(wbase + (size_t)n * nstr + (size_t)st * 512);
            }
        }
        #pragma unroll
        for (int sI = 0; sI < CH; ++sI) {
            acc0 = __builtin_amdgcn_mfma_f32_32x32x16_bf16(Ab[cur][sI][0], Bb[cur][sI], acc0, 0, 0, 0);
            acc1 = __builtin_amdgcn_mfma_f32_32x32x16_bf16(Ab[cur][sI][1], Bb[cur][sI], acc1, 0, 0, 0);
            acc2 = __builtin_amdgcn_mfma_f32_32x32x16_bf16(Ab[cur][sI][2], Bb[cur][sI], acc2, 0, 0, 0);
            acc3 = __builtin_amdgcn_mfma_f32_32x32x16_bf16(Ab[cur][sI][3], Bb[cur][sI], acc3, 0, 0, 0);
        }
    }

    // coef combine (per-wave partial), dump plane w to LDS
    const int b = bt * 32 + m;
    float4 cf = *(const float4*)(coef + b * 4);
    #pragma unroll
    for (int g = 0; g < 4; ++g)
        #pragma unroll
        for (int j = 0; j < 4; ++j) {
            int rI = g * 4 + j;
            float v = cf.x * acc0[rI] + cf.y * acc1[rI] + cf.z * acc2[rI] + cf.w * acc3[rI];
            red[w * 1024 + (8 * g + 4 * h + j) * 32 + m] = v;
        }
    __syncthreads();
    // wave w reduces + stores rows of group g=w
    {
        float vv[4];
        #pragma unroll
        for (int j = 0; j < 4; ++j) {
            int row = 8 * w + 4 * h + j;
            float v = red[row * 32 + m] + red[1024 + row * 32 + m]
                    + red[2048 + row * 32 + m] + red[3072 + row * 32 + m];
            if (ELU) v = (v > 0.f) ? v : expm1f(v);
            vv[j] = v;
        }
        if (OUT_BF16) {
            // o = ot*32 + 8w + 4h + j -> next layer's B-frag pos (NKS_next = 36)
            size_t off = (((size_t)bt * 36 + ot * 2 + (w >> 1)) * 64
                          + (w & 1) * 32 + m) * 8 + 4 * h;
            ushort4 pk;
            pk.x = f2bf(vv[0]); pk.y = f2bf(vv[1]); pk.z = f2bf(vv[2]); pk.w = f2bf(vv[3]);
            *(ushort4*)(HoutF + off) = pk;
        } else {
            int orow = ot * 32 + 8 * w + 4 * h;
            #pragma unroll
            for (int j = 0; j < 4; ++j)
                if (orow + j < Oreal) outF[(size_t)b * Oreal + orow + j] = vv[j];
        }
    }
}

__global__ void __launch_bounds__(256, 2) layer0_kernel(
    const unsigned short* __restrict__ Wf0, const unsigned short* __restrict__ xf,
    const float* __restrict__ coef, unsigned short* __restrict__ H1f)
{
    __shared__ float red[4 * 1024];
    layer_phase<true, true, 384, 512>(Wf0, xf, coef, H1f, nullptr, 512,
                                      red, blockIdx.x, threadIdx.x);
}
__global__ void __launch_bounds__(256, 2) layer1_kernel(
    const unsigned short* __restrict__ Wf1, const unsigned short* __restrict__ H1f,
    const float* __restrict__ coef, unsigned short* __restrict__ H2f)
{
    __shared__ float red[4 * 1024];
    layer_phase<true, true, 576, 512>(Wf1, H1f, coef, H2f, nullptr, 512,
                                      red, blockIdx.x, threadIdx.x);
}
__global__ void __launch_bounds__(256, 2) layer2_kernel(
    const unsigned short* __restrict__ Wf2, const unsigned short* __restrict__ H2f,
    const float* __restrict__ coef, float* __restrict__ outF)
{
    __shared__ float red[4 * 1024];
    layer_phase<false, false, 576, 320>(Wf2, H2f, coef, nullptr, outF, 311,
                                        red, blockIdx.x, threadIdx.x);
}

extern "C" void kernel_launch(void* const* d_in, const int* in_sizes, int n_in,
                              void* d_out, int out_size, void* d_ws, size_t ws_size,
                              hipStream_t stream) {
    (void)in_sizes; (void)n_in; (void)out_size; (void)ws_size;
    const float* x  = (const float*)d_in[0];
    const float* W0 = (const float*)d_in[1];
    const float* W1 = (const float*)d_in[2];
    const float* W2 = (const float*)d_in[3];
    const float* b0 = (const float*)d_in[4];
    const float* b1 = (const float*)d_in[5];
    const float* b2 = (const float*)d_in[6];
    float* out = (float*)d_out;

    char* wsb = (char*)d_ws;
    float*          coef = (float*)(wsb + 0);                  //   16384 B
    unsigned short* xf   = (unsigned short*)(wsb + 16384);     // (32,24,64,8)
    unsigned short* H1f  = (unsigned short*)(wsb + 802816);    // (32,36,64,8)
    unsigned short* H2f  = (unsigned short*)(wsb + 1982464);   // (32,36,64,8)
    unsigned short* Wf0  = (unsigned short*)(wsb + 3162112);   // (4,16,24,64,8)
    unsigned short* Wf1  = (unsigned short*)(wsb + 4734976);   // (4,16,36,64,8)
    unsigned short* Wf2  = (unsigned short*)(wsb + 7094272);   // (4,10,36,64,8)

    phaseA_kernel<<<dim3(1544), dim3(256), 0, stream>>>(
        x, W0, W1, W2, b0, b1, b2, coef, xf, H1f, H2f, Wf0, Wf1, Wf2);
    layer0_kernel<<<dim3(512), dim3(256), 0, stream>>>(Wf0, xf,  coef, H1f);
    layer1_kernel<<<dim3(512), dim3(256), 0, stream>>>(Wf1, H1f, coef, H2f);
    layer2_kernel<<<dim3(320), dim3(256), 0, stream>>>(Wf2, H2f, coef, out);
}